// Round 3
// baseline (219.667 us; speedup 1.0000x reference)
//
#include <hip/hip_runtime.h>

namespace {
constexpr int kB = 8;
constexpr int kC = 1025;
constexpr int kT = 3000;
constexpr int kBlock = 256;
constexpr int kChunk = 12;                 // 250 threads * 12 = 3000
constexpr int kActiveScan = kT / kChunk;   // 250
constexpr float kPi = 3.14159265358979323846f;   // 0x40490FDB == np.float32(np.pi)
constexpr float kTwoPi = 6.28318530717958647692f;
constexpr float kPiO2 = 1.57079632679489661923f;
}  // namespace

typedef float v4f __attribute__((ext_vector_type(4)));

// ~2-ulp atan2 on [0,1]-reduced argument (sleef atanf poly), rcp+1 Newton step.
__device__ __forceinline__ float fast_atan2f(float y, float x) {
  const float ax = __builtin_fabsf(x), ay = __builtin_fabsf(y);
  const float mx = fmaxf(ax, ay), mn = fminf(ax, ay);
  float r = __builtin_amdgcn_rcpf(mx);
  r = r * (2.0f - mx * r);                 // Newton: ~0.5 ulp reciprocal
  float t = mn * r;                        // in [0,1]
  if (mx == 0.0f) t = 0.0f;                // atan2(0,0) -> 0
  const float s = t * t;
  float p = 0.00282363896258175373f;
  p = fmaf(p, s, -0.0159569028764963150f);
  p = fmaf(p, s, 0.0425049886107444763f);
  p = fmaf(p, s, -0.0748900920152664185f);
  p = fmaf(p, s, 0.106347933411598206f);
  p = fmaf(p, s, -0.142027363181114197f);
  p = fmaf(p, s, 0.199926957488059998f);
  p = fmaf(p, s, -0.333331018686294556f);
  float a = fmaf(p * s, t, t);             // atan(t)
  a = (ay > ax) ? (kPiO2 - a) : a;
  a = (x < 0.0f) ? (kPi - a) : a;
  return copysignf(a, y);
}

__global__ __launch_bounds__(kBlock) void coherent_polar_kernel(
    const float* __restrict__ xr, const float* __restrict__ xi,
    float* __restrict__ out) {
  __shared__ float s_last[kBlock];   // last raw phase of each thread's chunk
  __shared__ float s_wsum[4];
  __shared__ float s_wmin[4];
  __shared__ float s_wmax[4];

  const int row = blockIdx.x;              // [0, B*C)
  const int b = row / kC;
  const int c = row - b * kC;
  const float* re = xr + (size_t)row * kT;
  const float* im = xi + (size_t)row * kT;
  float* mag_out = out + ((size_t)b * (2 * kC) + c) * kT;
  float* ph_out  = out + ((size_t)b * (2 * kC) + kC + c) * kT;

  const int tid = threadIdx.x;
  const int lane = tid & 63;
  const int wave = tid >> 6;
  const bool active = tid < kActiveScan;
  const int a0 = tid * kChunk;             // chunk start (multiple of 4 -> 16B aligned)

  // ---- Pass 1: per-thread contiguous chunk. 3x float4 loads of re/im,
  // magnitude straight to global (nontemporal), phases to registers.
  float ph[kChunk];
  if (active) {
    v4f r4[3], i4[3];
#pragma unroll
    for (int s = 0; s < 3; ++s) {
      r4[s] = *reinterpret_cast<const v4f*>(re + a0 + 4 * s);
      i4[s] = *reinterpret_cast<const v4f*>(im + a0 + 4 * s);
    }
#pragma unroll
    for (int s = 0; s < 3; ++s) {
      v4f m4;
      m4.x = sqrtf(fmaf(r4[s].x, r4[s].x, i4[s].x * i4[s].x));
      m4.y = sqrtf(fmaf(r4[s].y, r4[s].y, i4[s].y * i4[s].y));
      m4.z = sqrtf(fmaf(r4[s].z, r4[s].z, i4[s].z * i4[s].z));
      m4.w = sqrtf(fmaf(r4[s].w, r4[s].w, i4[s].w * i4[s].w));
      __builtin_nontemporal_store(m4, reinterpret_cast<v4f*>(mag_out + a0 + 4 * s));
      ph[4 * s + 0] = fast_atan2f(i4[s].x, r4[s].x);
      ph[4 * s + 1] = fast_atan2f(i4[s].y, r4[s].y);
      ph[4 * s + 2] = fast_atan2f(i4[s].z, r4[s].z);
      ph[4 * s + 3] = fast_atan2f(i4[s].w, r4[s].w);
    }
  }

  // ---- Boundary handoff: thread t needs raw ph_last of thread t-1.
  s_last[tid] = active ? ph[kChunk - 1] : 0.0f;
  __syncthreads();

  // ---- Local unwrap: run includes the boundary step (k=0 vs prev chunk).
  float run = 0.0f;
  if (active) {
    float p = (tid == 0) ? ph[0] : s_last[tid - 1];
#pragma unroll
    for (int k = 0; k < kChunk; ++k) {
      const float cur = ph[k];
      const float d = cur - p;
      p = cur;
      float step = 0.0f;
      if (d < -kPi) step = kTwoPi;
      else if (d > kPi) step = -kTwoPi;
      run += step;
      ph[k] = cur + run;                   // raw + local inclusive correction
    }
  }
  const float total = active ? run : 0.0f;

  // ---- Wave-level inclusive scan of chunk totals.
  float inc = total;
#pragma unroll
  for (int d = 1; d < 64; d <<= 1) {
    const float n = __shfl_up(inc, d);
    if (lane >= d) inc += n;
  }
  const float wave_rel = inc - total;      // exclusive prefix within wave

  // ---- Wave-relative min/max of corrected values.
  float mn = __builtin_inff();
  float mx = -__builtin_inff();
  if (active) {
#pragma unroll
    for (int k = 0; k < kChunk; ++k) {
      const float u = ph[k] + wave_rel;
      mn = fminf(mn, u);
      mx = fmaxf(mx, u);
    }
  }
#pragma unroll
  for (int m = 32; m >= 1; m >>= 1) {
    mn = fminf(mn, __shfl_xor(mn, m));
    mx = fmaxf(mx, __shfl_xor(mx, m));
  }
  if (lane == 63) s_wsum[wave] = inc;      // wave total of steps
  if (lane == 0) { s_wmin[wave] = mn; s_wmax[wave] = mx; }
  __syncthreads();

  // ---- Cross-wave: prefixes, global min/max, normalize, store.
  const float w0 = s_wsum[0], w1 = s_wsum[1], w2 = s_wsum[2];
  const float wp1 = w0, wp2 = w0 + w1, wp3 = w0 + w1 + w2;
  float gmn = s_wmin[0];
  float gmx = s_wmax[0];
  gmn = fminf(gmn, s_wmin[1] + wp1); gmx = fmaxf(gmx, s_wmax[1] + wp1);
  gmn = fminf(gmn, s_wmin[2] + wp2); gmx = fmaxf(gmx, s_wmax[2] + wp2);
  gmn = fminf(gmn, s_wmin[3] + wp3); gmx = fmaxf(gmx, s_wmax[3] + wp3);
  const float wave_pref = (wave == 0) ? 0.0f : ((wave == 1) ? wp1 : ((wave == 2) ? wp2 : wp3));
  const float base = wave_rel + wave_pref - gmn;
  const float inv = 1.0f / (gmx - gmn + 1e-8f);

  if (active) {
#pragma unroll
    for (int k = 0; k < kChunk; k += 4) {
      v4f o;
      o.x = (ph[k + 0] + base) * inv;
      o.y = (ph[k + 1] + base) * inv;
      o.z = (ph[k + 2] + base) * inv;
      o.w = (ph[k + 3] + base) * inv;
      __builtin_nontemporal_store(o, reinterpret_cast<v4f*>(ph_out + a0 + k));
    }
  }
}

extern "C" void kernel_launch(void* const* d_in, const int* in_sizes, int n_in,
                              void* d_out, int out_size, void* d_ws, size_t ws_size,
                              hipStream_t stream) {
  const float* xr = (const float*)d_in[0];
  const float* xi = (const float*)d_in[1];
  float* out = (float*)d_out;
  coherent_polar_kernel<<<dim3(kB * kC), dim3(kBlock), 0, stream>>>(xr, xi, out);
}

// Round 4
// 88.306 us; speedup vs baseline: 2.4876x; 2.4876x over previous
//
#include <hip/hip_runtime.h>

namespace {
constexpr int kB = 8;
constexpr int kC = 1025;
constexpr int kT = 3000;
constexpr int kBlock = 256;
constexpr int kChunk = 12;                 // 250 threads * 12 = 3000
constexpr int kActiveScan = kT / kChunk;   // 250
constexpr float kPi = 3.14159265358979323846f;   // 0x40490FDB == np.float32(np.pi)
constexpr float kTwoPi = 6.28318530717958647692f;
constexpr float kPiO2 = 1.57079632679489661923f;
}  // namespace

typedef float v4f __attribute__((ext_vector_type(4)));

// ~2-ulp atan2 on [0,1]-reduced argument (sleef atanf poly), rcp+1 Newton step.
__device__ __forceinline__ float fast_atan2f(float y, float x) {
  const float ax = __builtin_fabsf(x), ay = __builtin_fabsf(y);
  const float mx = fmaxf(ax, ay), mn = fminf(ax, ay);
  float r = __builtin_amdgcn_rcpf(mx);
  r = r * (2.0f - mx * r);                 // Newton: ~0.5 ulp reciprocal
  float t = mn * r;                        // in [0,1]
  if (mx == 0.0f) t = 0.0f;                // atan2(0,0) -> 0
  const float s = t * t;
  float p = 0.00282363896258175373f;
  p = fmaf(p, s, -0.0159569028764963150f);
  p = fmaf(p, s, 0.0425049886107444763f);
  p = fmaf(p, s, -0.0748900920152664185f);
  p = fmaf(p, s, 0.106347933411598206f);
  p = fmaf(p, s, -0.142027363181114197f);
  p = fmaf(p, s, 0.199926957488059998f);
  p = fmaf(p, s, -0.333331018686294556f);
  float a = fmaf(p * s, t, t);             // atan(t)
  a = (ay > ax) ? (kPiO2 - a) : a;
  a = (x < 0.0f) ? (kPi - a) : a;
  return copysignf(a, y);
}

__global__ __launch_bounds__(kBlock) void coherent_polar_kernel(
    const float* __restrict__ xr, const float* __restrict__ xi,
    float* __restrict__ out) {
  __shared__ float s_last[kBlock];   // last raw phase of each thread's chunk
  __shared__ float s_wsum[4];
  __shared__ float s_wmin[4];
  __shared__ float s_wmax[4];

  const int row = blockIdx.x;              // [0, B*C)
  const int b = row / kC;
  const int c = row - b * kC;
  const float* re = xr + (size_t)row * kT;
  const float* im = xi + (size_t)row * kT;
  float* mag_out = out + ((size_t)b * (2 * kC) + c) * kT;
  float* ph_out  = out + ((size_t)b * (2 * kC) + kC + c) * kT;

  const int tid = threadIdx.x;
  const int lane = tid & 63;
  const int wave = tid >> 6;
  const bool active = tid < kActiveScan;
  const int a0 = tid * kChunk;             // chunk start (multiple of 4 -> 16B aligned)

  // ---- Pass 1: per-thread contiguous chunk. 3x float4 loads of re/im,
  // magnitude straight to global (cached stores: L2 merges the 48B-stride
  // per-lane pattern into full lines — nt stores caused 2.4x write amp here),
  // phases to registers.
  float ph[kChunk];
  if (active) {
    v4f r4[3], i4[3];
#pragma unroll
    for (int s = 0; s < 3; ++s) {
      r4[s] = *reinterpret_cast<const v4f*>(re + a0 + 4 * s);
      i4[s] = *reinterpret_cast<const v4f*>(im + a0 + 4 * s);
    }
#pragma unroll
    for (int s = 0; s < 3; ++s) {
      v4f m4;
      m4.x = sqrtf(fmaf(r4[s].x, r4[s].x, i4[s].x * i4[s].x));
      m4.y = sqrtf(fmaf(r4[s].y, r4[s].y, i4[s].y * i4[s].y));
      m4.z = sqrtf(fmaf(r4[s].z, r4[s].z, i4[s].z * i4[s].z));
      m4.w = sqrtf(fmaf(r4[s].w, r4[s].w, i4[s].w * i4[s].w));
      *reinterpret_cast<v4f*>(mag_out + a0 + 4 * s) = m4;
      ph[4 * s + 0] = fast_atan2f(i4[s].x, r4[s].x);
      ph[4 * s + 1] = fast_atan2f(i4[s].y, r4[s].y);
      ph[4 * s + 2] = fast_atan2f(i4[s].z, r4[s].z);
      ph[4 * s + 3] = fast_atan2f(i4[s].w, r4[s].w);
    }
  }

  // ---- Boundary handoff: thread t needs raw ph_last of thread t-1.
  s_last[tid] = active ? ph[kChunk - 1] : 0.0f;
  __syncthreads();

  // ---- Local unwrap: run includes the boundary step (k=0 vs prev chunk).
  float run = 0.0f;
  if (active) {
    float p = (tid == 0) ? ph[0] : s_last[tid - 1];
#pragma unroll
    for (int k = 0; k < kChunk; ++k) {
      const float cur = ph[k];
      const float d = cur - p;
      p = cur;
      float step = 0.0f;
      if (d < -kPi) step = kTwoPi;
      else if (d > kPi) step = -kTwoPi;
      run += step;
      ph[k] = cur + run;                   // raw + local inclusive correction
    }
  }
  const float total = active ? run : 0.0f;

  // ---- Wave-level inclusive scan of chunk totals.
  float inc = total;
#pragma unroll
  for (int d = 1; d < 64; d <<= 1) {
    const float n = __shfl_up(inc, d);
    if (lane >= d) inc += n;
  }
  const float wave_rel = inc - total;      // exclusive prefix within wave

  // ---- Wave-relative min/max of corrected values.
  float mn = __builtin_inff();
  float mx = -__builtin_inff();
  if (active) {
#pragma unroll
    for (int k = 0; k < kChunk; ++k) {
      const float u = ph[k] + wave_rel;
      mn = fminf(mn, u);
      mx = fmaxf(mx, u);
    }
  }
#pragma unroll
  for (int m = 32; m >= 1; m >>= 1) {
    mn = fminf(mn, __shfl_xor(mn, m));
    mx = fmaxf(mx, __shfl_xor(mx, m));
  }
  if (lane == 63) s_wsum[wave] = inc;      // wave total of steps
  if (lane == 0) { s_wmin[wave] = mn; s_wmax[wave] = mx; }
  __syncthreads();

  // ---- Cross-wave: prefixes, global min/max, normalize, store.
  const float w0 = s_wsum[0], w1 = s_wsum[1], w2 = s_wsum[2];
  const float wp1 = w0, wp2 = w0 + w1, wp3 = w0 + w1 + w2;
  float gmn = s_wmin[0];
  float gmx = s_wmax[0];
  gmn = fminf(gmn, s_wmin[1] + wp1); gmx = fmaxf(gmx, s_wmax[1] + wp1);
  gmn = fminf(gmn, s_wmin[2] + wp2); gmx = fmaxf(gmx, s_wmax[2] + wp2);
  gmn = fminf(gmn, s_wmin[3] + wp3); gmx = fmaxf(gmx, s_wmax[3] + wp3);
  const float wave_pref = (wave == 0) ? 0.0f : ((wave == 1) ? wp1 : ((wave == 2) ? wp2 : wp3));
  const float base = wave_rel + wave_pref - gmn;
  const float inv = 1.0f / (gmx - gmn + 1e-8f);

  if (active) {
#pragma unroll
    for (int k = 0; k < kChunk; k += 4) {
      v4f o;
      o.x = (ph[k + 0] + base) * inv;
      o.y = (ph[k + 1] + base) * inv;
      o.z = (ph[k + 2] + base) * inv;
      o.w = (ph[k + 3] + base) * inv;
      *reinterpret_cast<v4f*>(ph_out + a0 + k) = o;
    }
  }
}

extern "C" void kernel_launch(void* const* d_in, const int* in_sizes, int n_in,
                              void* d_out, int out_size, void* d_ws, size_t ws_size,
                              hipStream_t stream) {
  const float* xr = (const float*)d_in[0];
  const float* xi = (const float*)d_in[1];
  float* out = (float*)d_out;
  coherent_polar_kernel<<<dim3(kB * kC), dim3(kBlock), 0, stream>>>(xr, xi, out);
}

// Round 5
// 80.387 us; speedup vs baseline: 2.7326x; 1.0985x over previous
//
#include <hip/hip_runtime.h>

namespace {
constexpr int kB = 8;
constexpr int kC = 1025;
constexpr int kT = 3000;
constexpr int kBlockThreads = 768;          // 12 waves
constexpr int kWaves = kBlockThreads / 64;
constexpr int kActive = kT / 4;             // 750 threads own one float4 each
constexpr float kPi = 3.14159265358979323846f;   // 0x40490FDB == np.float32(np.pi)
constexpr float kTwoPi = 6.28318530717958647692f;
constexpr float kPiO2 = 1.57079632679489661923f;
}  // namespace

typedef float v4f __attribute__((ext_vector_type(4)));

// ~2-ulp atan2 on [0,1]-reduced argument (sleef atanf poly), rcp+1 Newton step.
__device__ __forceinline__ float fast_atan2f(float y, float x) {
  const float ax = __builtin_fabsf(x), ay = __builtin_fabsf(y);
  const float mx = fmaxf(ax, ay), mn = fminf(ax, ay);
  float r = __builtin_amdgcn_rcpf(mx);
  r = r * (2.0f - mx * r);                 // Newton: ~0.5 ulp reciprocal
  float t = mn * r;                        // in [0,1]
  if (mx == 0.0f) t = 0.0f;                // atan2(0,0) -> 0
  const float s = t * t;
  float p = 0.00282363896258175373f;
  p = fmaf(p, s, -0.0159569028764963150f);
  p = fmaf(p, s, 0.0425049886107444763f);
  p = fmaf(p, s, -0.0748900920152664185f);
  p = fmaf(p, s, 0.106347933411598206f);
  p = fmaf(p, s, -0.142027363181114197f);
  p = fmaf(p, s, 0.199926957488059998f);
  p = fmaf(p, s, -0.333331018686294556f);
  float a = fmaf(p * s, t, t);             // atan(t)
  a = (ay > ax) ? (kPiO2 - a) : a;
  a = (x < 0.0f) ? (kPi - a) : a;
  return copysignf(a, y);
}

__global__ __launch_bounds__(kBlockThreads) void coherent_polar_kernel(
    const float* __restrict__ xr, const float* __restrict__ xi,
    float* __restrict__ out) {
  __shared__ float s_last[kBlockThreads];   // last raw phase of each thread's float4
  __shared__ float s_wsum[kWaves];
  __shared__ float s_wmin[kWaves];
  __shared__ float s_wmax[kWaves];

  const int row = blockIdx.x;              // [0, B*C)
  const int b = row / kC;
  const int c = row - b * kC;
  const float* re = xr + (size_t)row * kT;
  const float* im = xi + (size_t)row * kT;
  float* mag_out = out + ((size_t)b * (2 * kC) + c) * kT;
  float* ph_out  = out + ((size_t)b * (2 * kC) + kC + c) * kT;

  const int tid = threadIdx.x;
  const int lane = tid & 63;
  const int wave = tid >> 6;
  const bool active = tid < kActive;
  const int a0 = tid * 4;                  // fully coalesced: lane-consecutive float4

  // ---- Pass 1: one float4 of re/im per thread (wave-contiguous 1KB loads),
  // magnitude straight to global (coalesced), phases in registers.
  float ph[4];
  if (active) {
    const v4f r4 = *reinterpret_cast<const v4f*>(re + a0);
    const v4f i4 = *reinterpret_cast<const v4f*>(im + a0);
    v4f m4;
    m4.x = sqrtf(fmaf(r4.x, r4.x, i4.x * i4.x));
    m4.y = sqrtf(fmaf(r4.y, r4.y, i4.y * i4.y));
    m4.z = sqrtf(fmaf(r4.z, r4.z, i4.z * i4.z));
    m4.w = sqrtf(fmaf(r4.w, r4.w, i4.w * i4.w));
    *reinterpret_cast<v4f*>(mag_out + a0) = m4;
    ph[0] = fast_atan2f(i4.x, r4.x);
    ph[1] = fast_atan2f(i4.y, r4.y);
    ph[2] = fast_atan2f(i4.z, r4.z);
    ph[3] = fast_atan2f(i4.w, r4.w);
  }

  // ---- Boundary handoff: thread t needs raw last phase of thread t-1.
  s_last[tid] = active ? ph[3] : 0.0f;
  __syncthreads();

  // ---- Local unwrap of 4 elements (boundary step vs prev thread included).
  float run = 0.0f;
  if (active) {
    float p = (tid == 0) ? ph[0] : s_last[tid - 1];
#pragma unroll
    for (int k = 0; k < 4; ++k) {
      const float cur = ph[k];
      const float d = cur - p;
      p = cur;
      float step = 0.0f;
      if (d < -kPi) step = kTwoPi;
      else if (d > kPi) step = -kTwoPi;
      run += step;
      ph[k] = cur + run;                   // raw + local inclusive correction
    }
  }
  const float total = active ? run : 0.0f;

  // ---- Wave-level inclusive scan of per-thread step totals.
  float inc = total;
#pragma unroll
  for (int d = 1; d < 64; d <<= 1) {
    const float n = __shfl_up(inc, d);
    if (lane >= d) inc += n;
  }
  const float wave_rel = inc - total;      // exclusive prefix within wave
  if (lane == 63) s_wsum[wave] = inc;      // wave total
  __syncthreads();

  // ---- Cross-wave exclusive prefix (12 broadcast reads).
  float wave_pref = 0.0f;
#pragma unroll
  for (int w = 0; w < kWaves - 1; ++w)
    if (w < wave) wave_pref += s_wsum[w];
  const float corr = wave_rel + wave_pref;

  // ---- Globally-corrected values; block min/max reduce.
  float mn = __builtin_inff();
  float mx = -__builtin_inff();
  if (active) {
#pragma unroll
    for (int k = 0; k < 4; ++k) {
      ph[k] += corr;
      mn = fminf(mn, ph[k]);
      mx = fmaxf(mx, ph[k]);
    }
  }
#pragma unroll
  for (int m = 32; m >= 1; m >>= 1) {
    mn = fminf(mn, __shfl_xor(mn, m));
    mx = fmaxf(mx, __shfl_xor(mx, m));
  }
  if (lane == 0) { s_wmin[wave] = mn; s_wmax[wave] = mx; }
  __syncthreads();
  mn = s_wmin[0];
  mx = s_wmax[0];
#pragma unroll
  for (int w = 1; w < kWaves; ++w) {
    mn = fminf(mn, s_wmin[w]);
    mx = fmaxf(mx, s_wmax[w]);
  }
  const float inv = 1.0f / (mx - mn + 1e-8f);

  // ---- Normalized phase: one coalesced float4 store per thread.
  if (active) {
    v4f o;
    o.x = (ph[0] - mn) * inv;
    o.y = (ph[1] - mn) * inv;
    o.z = (ph[2] - mn) * inv;
    o.w = (ph[3] - mn) * inv;
    *reinterpret_cast<v4f*>(ph_out + a0) = o;
  }
}

extern "C" void kernel_launch(void* const* d_in, const int* in_sizes, int n_in,
                              void* d_out, int out_size, void* d_ws, size_t ws_size,
                              hipStream_t stream) {
  const float* xr = (const float*)d_in[0];
  const float* xi = (const float*)d_in[1];
  float* out = (float*)d_out;
  coherent_polar_kernel<<<dim3(kB * kC), dim3(kBlockThreads), 0, stream>>>(xr, xi, out);
}